// Round 5
// baseline (585.059 us; speedup 1.0000x reference)
//
#include <hip/hip_runtime.h>

#define U 4096
#define S 8192
#define D 32
#define NUM_REGIONS 128
#define GA 0.1f

#define TUSERS 32      // users per block
#define TITEMS 256     // items per block
#define THREADS 256
#define GRID_X (U / TUSERS)   // 128
#define GRID_Y (S / TITEMS)   // 32
#define NBLOCKS (GRID_X * GRID_Y)

typedef short short8 __attribute__((ext_vector_type(8)));
typedef float f32x4 __attribute__((ext_vector_type(4)));

// fp32 -> bf16, round-to-nearest-even (inputs are tame gaussians; no NaN path)
__device__ __forceinline__ unsigned short f2bf(float f) {
    unsigned u = __float_as_uint(f);
    return (unsigned short)((u + 0x7FFFu + ((u >> 16) & 1u)) >> 16);
}

// ---------------- K1: bf16 conversion + region sums/counts (atomics) --------

__global__ __launch_bounds__(256) void prep_kernel(
    const float* __restrict__ user_emb,
    const float* __restrict__ item_emb,
    const int* __restrict__ region_index,
    float* __restrict__ sums,          // [R, D]
    float* __restrict__ counts,        // [R]
    unsigned short* __restrict__ user_bf16,   // [U, D]
    unsigned short* __restrict__ item_bf16) { // [S, D]
    const int g = blockIdx.x * 256 + threadIdx.x;  // 0..32767

    {
        float4 v = ((const float4*)user_emb)[g];
        ushort4 o;
        o.x = f2bf(v.x); o.y = f2bf(v.y); o.z = f2bf(v.z); o.w = f2bf(v.w);
        ((ushort4*)user_bf16)[g] = o;
        int e0 = g * 4;
        int u = e0 >> 5, d = e0 & 31;
        int r = region_index[u];
        float* dst = &sums[r * D + d];
        atomicAdd(dst + 0, v.x);
        atomicAdd(dst + 1, v.y);
        atomicAdd(dst + 2, v.z);
        atomicAdd(dst + 3, v.w);
    }
    if (g < U) atomicAdd(&counts[region_index[g]], 1.0f);

    {
        float4 a = ((const float4*)item_emb)[2 * g];
        float4 b = ((const float4*)item_emb)[2 * g + 1];
        ushort4 oa, ob;
        oa.x = f2bf(a.x); oa.y = f2bf(a.y); oa.z = f2bf(a.z); oa.w = f2bf(a.w);
        ob.x = f2bf(b.x); ob.y = f2bf(b.y); ob.z = f2bf(b.z); ob.w = f2bf(b.w);
        ((ushort4*)item_bf16)[2 * g]     = oa;
        ((ushort4*)item_bf16)[2 * g + 1] = ob;
    }
}

// ---------------- K2: MFMA masked-MSE + LDS re-layout epilogue ----------------
// Block tile 32 users x 256 items, one MFMA per 16x16 subtile (K=D=32).
// Predictions round-trip through LDS so the 402 MB mask/qos/weight stream is
// read as float4, 64 consecutive lanes = 1 whole row of the tile (1 KB/instr).

__global__ __launch_bounds__(THREADS, 4) void mse_kernel(
    const float* __restrict__ user_emb,
    const unsigned short* __restrict__ user_bf16,
    const unsigned short* __restrict__ item_bf16,
    const int* __restrict__ train_mask,
    const float* __restrict__ true_qos,
    const float* __restrict__ us_lossweight,
    const int* __restrict__ region_index,
    const float* __restrict__ sums,
    const float* __restrict__ counts,
    float* __restrict__ loss_acc,
    unsigned int* __restrict__ done_counter,
    float* __restrict__ out) {
    // 32 KB shared: staging tiles aliased over the prediction tile
    __shared__ __align__(16) float predL[TUSERS * TITEMS];  // 32 KB
    unsigned short* iL = (unsigned short*)predL;            // 16 KB item tile
    unsigned short* uL = ((unsigned short*)predL) + TITEMS * D;  // 2 KB user tile
    __shared__ float wp[THREADS / 64];

    const int tid  = threadIdx.x;
    const int wave = tid >> 6;
    const int lane = tid & 63;
    const int ub = blockIdx.x * TUSERS;
    const int sb = blockIdx.y * TITEMS;

    // stage tiles (coalesced)
    ((ushort4*)uL)[tid] = ((const ushort4*)(user_bf16 + ub * D))[tid];
    {
        const int4* src = (const int4*)(item_bf16 + (size_t)sb * D);
        int4* dst = (int4*)iL;
        #pragma unroll
        for (int i = 0; i < 4; i++) dst[i * 256 + tid] = src[i * 256 + tid];
    }

    float lacc = 0.0f;

    // fused LOO region loss: only the y==0 slab (32 users x 32 dims)
    if (blockIdx.y == 0) {
        #pragma unroll
        for (int i = tid; i < TUSERS * D; i += THREADS) {
            int u = ub + (i >> 5), d = i & 31;
            int r = region_index[u];
            float c = counts[r];
            if (c > 1.0f) {
                float e = user_emb[u * D + d];
                float loo = (sums[r * D + d] - e) / fmaxf(c - 1.0f, 1.0f);
                lacc += GA * fabsf(e - loo);
            }
        }
    }

    __syncthreads();

    const int row16 = lane & 15;
    const int quad  = lane >> 4;
    const int koff  = quad * 8;

    // fragments (verified layouts m89/m91): A/B[idx=lane&15][k=(lane>>4)*8+j]
    short8 a0 = *(const short8*)&uL[(row16)      * D + koff];
    short8 a1 = *(const short8*)&uL[(16 + row16) * D + koff];
    const int ibase = wave * 64;
    short8 b0 = *(const short8*)&iL[(ibase +  0 + row16) * D + koff];
    short8 b1 = *(const short8*)&iL[(ibase + 16 + row16) * D + koff];
    short8 b2 = *(const short8*)&iL[(ibase + 32 + row16) * D + koff];
    short8 b3 = *(const short8*)&iL[(ibase + 48 + row16) * D + koff];

    __syncthreads();  // everyone's fragments loaded before predL overwrites iL

    f32x4 acc[2][4];
    #pragma unroll
    for (int i = 0; i < 2; i++)
        #pragma unroll
        for (int j = 0; j < 4; j++) acc[i][j] = (f32x4)0.0f;

    acc[0][0] = __builtin_amdgcn_mfma_f32_16x16x32_bf16(a0, b0, acc[0][0], 0, 0, 0);
    acc[0][1] = __builtin_amdgcn_mfma_f32_16x16x32_bf16(a0, b1, acc[0][1], 0, 0, 0);
    acc[0][2] = __builtin_amdgcn_mfma_f32_16x16x32_bf16(a0, b2, acc[0][2], 0, 0, 0);
    acc[0][3] = __builtin_amdgcn_mfma_f32_16x16x32_bf16(a0, b3, acc[0][3], 0, 0, 0);
    acc[1][0] = __builtin_amdgcn_mfma_f32_16x16x32_bf16(a1, b0, acc[1][0], 0, 0, 0);
    acc[1][1] = __builtin_amdgcn_mfma_f32_16x16x32_bf16(a1, b1, acc[1][1], 0, 0, 0);
    acc[1][2] = __builtin_amdgcn_mfma_f32_16x16x32_bf16(a1, b2, acc[1][2], 0, 0, 0);
    acc[1][3] = __builtin_amdgcn_mfma_f32_16x16x32_bf16(a1, b3, acc[1][3], 0, 0, 0);

    // scatter predictions to LDS (C/D layout: col=lane&15, row=quad*4+reg)
    #pragma unroll
    for (int ut = 0; ut < 2; ut++)
        #pragma unroll
        for (int it = 0; it < 4; it++) {
            const int n = ibase + it * 16 + row16;
            #pragma unroll
            for (int r = 0; r < 4; r++)
                predL[(ut * 16 + quad * 4 + r) * TITEMS + n] = acc[ut][it][r];
        }
    __syncthreads();

    // streaming epilogue: wave owns rows [8w, 8w+8); lane covers items 4l..4l+3.
    // All loads float4/int4, 64 lanes span one full 1 KB row — perfect coalescing.
    const int colbase = 4 * lane;
    float l0 = 0.f, l1 = 0.f, l2 = 0.f, l3 = 0.f;
    #pragma unroll
    for (int rr = 0; rr < 8; rr++) {
        const int m = wave * 8 + rr;
        const size_t gix = (size_t)(ub + m) * S + sb + colbase;
        int4   mk = *(const int4*)(train_mask + gix);
        float4 q  = *(const float4*)(true_qos + gix);
        float4 w  = *(const float4*)(us_lossweight + gix);
        float4 p  = *(const float4*)&predL[m * TITEMS + colbase];
        float e0 = p.x * (float)mk.x - q.x;
        float e1 = p.y * (float)mk.y - q.y;
        float e2 = p.z * (float)mk.z - q.z;
        float e3 = p.w * (float)mk.w - q.w;
        l0 = fmaf(w.x * e0, e0, l0);
        l1 = fmaf(w.y * e1, e1, l1);
        l2 = fmaf(w.z * e2, e2, l2);
        l3 = fmaf(w.w * e3, e3, l3);
    }
    lacc += (l0 + l1) + (l2 + l3);

    // wave64 reduce + one atomic per block; last block finalizes
    #pragma unroll
    for (int off = 32; off > 0; off >>= 1) lacc += __shfl_down(lacc, off, 64);
    if (lane == 0) wp[wave] = lacc;
    __syncthreads();
    if (tid == 0) {
        float t = wp[0] + wp[1] + wp[2] + wp[3];
        atomicAdd(loss_acc, t);
        __threadfence();
        unsigned int nd = atomicAdd(done_counter, 1u);
        if (nd == NBLOCKS - 1) {
            out[0] = atomicAdd(loss_acc, 0.0f);  // device-coherent read
        }
    }
}

extern "C" void kernel_launch(void* const* d_in, const int* in_sizes, int n_in,
                              void* d_out, int out_size, void* d_ws, size_t ws_size,
                              hipStream_t stream) {
    const float* user_emb      = (const float*)d_in[0];
    const float* item_emb      = (const float*)d_in[1];
    const int*   train_mask    = (const int*)d_in[2];
    const float* true_qos      = (const float*)d_in[3];
    const float* us_lossweight = (const float*)d_in[4];
    const int*   region_index  = (const int*)d_in[5];
    float* out = (float*)d_out;

    float* ws       = (float*)d_ws;
    float* sums     = ws;                       // R*D = 4096 floats
    float* counts   = sums + NUM_REGIONS * D;   // 128
    float* loss_acc = counts + NUM_REGIONS;     // 1
    unsigned int* done_counter = (unsigned int*)(loss_acc + 1);
    unsigned short* user_bf16 = (unsigned short*)(ws + 4240);  // 256 KB
    unsigned short* item_bf16 = user_bf16 + (size_t)U * D;     // 512 KB

    hipMemsetAsync(d_ws, 0, 4226 * sizeof(float), stream);

    prep_kernel<<<128, 256, 0, stream>>>(user_emb, item_emb, region_index,
                                         sums, counts, user_bf16, item_bf16);

    dim3 grid(GRID_X, GRID_Y);
    mse_kernel<<<grid, THREADS, 0, stream>>>(
        user_emb, user_bf16, item_bf16, train_mask, true_qos, us_lossweight,
        region_index, sums, counts, loss_acc, done_counter, out);
}